// Round 5
// baseline (461.875 us; speedup 1.0000x reference)
//
#include <hip/hip_runtime.h>
#include <hip/hip_bf16.h>
#include <cstdint>
#include <cstddef>

#define B_DIM  8192
#define D_DIM  1024
#define H_DIM  4096
#define H2_DIM 8192

using bf16 = __hip_bfloat16;
typedef __attribute__((ext_vector_type(8))) short bf16x8;   // 8 bf16 in 4 VGPRs
typedef __attribute__((ext_vector_type(4))) float f32x4;    // MFMA accumulator

// ---------------------------------------------------------------- cast x -> bf16
__global__ __launch_bounds__(256) void cast_f32_to_bf16(const float* __restrict__ in,
                                                        bf16* __restrict__ out, int n_vec8) {
    int i = blockIdx.x * 256 + threadIdx.x;
    if (i >= n_vec8) return;
    const float4* src = reinterpret_cast<const float4*>(in) + (size_t)i * 2;
    float4 a = src[0], b = src[1];
    union { bf16 h[8]; int4 u; } r;
    r.h[0] = __float2bfloat16(a.x); r.h[1] = __float2bfloat16(a.y);
    r.h[2] = __float2bfloat16(a.z); r.h[3] = __float2bfloat16(a.w);
    r.h[4] = __float2bfloat16(b.x); r.h[5] = __float2bfloat16(b.y);
    r.h[6] = __float2bfloat16(b.z); r.h[7] = __float2bfloat16(b.w);
    reinterpret_cast<int4*>(out)[i] = r.u;
}

// ---------------------------------------------------------------- router p = sigmoid(x.Wr + br)
__global__ __launch_bounds__(256) void router_kernel(const float* __restrict__ x,
                                                     const float* __restrict__ Wr,
                                                     const float* __restrict__ br,
                                                     float* __restrict__ p) {
    int wave = threadIdx.x >> 6, lane = threadIdx.x & 63;
    int row = blockIdx.x * 4 + wave;
    const float* xr = x + (size_t)row * D_DIM;
    float sum = 0.f;
#pragma unroll
    for (int it = 0; it < 4; ++it) {
        int k = it * 256 + lane * 4;
        float4 xv = *reinterpret_cast<const float4*>(xr + k);
        float4 wv = *reinterpret_cast<const float4*>(Wr + k);
        sum += xv.x * wv.x + xv.y * wv.y + xv.z * wv.z + xv.w * wv.w;
    }
#pragma unroll
    for (int off = 32; off >= 1; off >>= 1) sum += __shfl_down(sum, off, 64);
    if (lane == 0) p[row] = 1.f / (1.f + expf(-(sum + br[0])));
}

// ---------------------------------------------------------------- transpose f32 [R][C] -> bf16 dst[c*dstLD + r]
__global__ __launch_bounds__(256) void transpose_cast_kernel(const float* __restrict__ src,
                                                             int R, int C,
                                                             bf16* __restrict__ dst, int dstLD) {
    __shared__ float tile[32][33];
    int c0 = blockIdx.x * 32, r0 = blockIdx.y * 32;
    int tx = threadIdx.x & 31, ty = threadIdx.x >> 5;  // ty: 0..7
#pragma unroll
    for (int i = 0; i < 32; i += 8)
        tile[ty + i][tx] = src[(size_t)(r0 + ty + i) * C + c0 + tx];
    __syncthreads();
#pragma unroll
    for (int i = 0; i < 32; i += 8)
        dst[(size_t)(c0 + ty + i) * dstLD + r0 + tx] = __float2bfloat16(tile[tx][ty + i]);
}

// ================================================================ 8-phase counted-vmcnt GEMM
// C = A[M,K] * Bt[N,K]^T. BM=256, BN=NBH*128, BK=64, 512 threads (8 waves, 2M x 4N).
// K-tile buffer = NHALF half-tiles of [128 rows][64 bf16] (A0,A1,B0[,B1]); 2 buffers.
// Per K-tile: PPT phases of exactly 16 MFMA; B-frags read at tile's first phase.
// T2 swizzle: LDS 16B-granule c at row R holds global granule c^(R&7); source pre-swizzled
// (global_load_lds dest stays linear); ds_read applies same XOR -> conflict-free (verified 0).
// Stage slots chosen so every staged half has >=2-phase landing margin; waits are
// vmcnt(4)/vmcnt(2) mid-loop (NEVER 0): loads stay in flight across all barriers (T4).
template<int NBH, int EPI>
__global__ __launch_bounds__(512, 2) void gemm8(const bf16* __restrict__ A,
                                                const bf16* __restrict__ Bt,
                                                void* __restrict__ Cout,
                                                int N, int K, int NT, int nbx,
                                                const float* __restrict__ p,
                                                const float* __restrict__ bias_l,
                                                const float* __restrict__ bias_r) {
    constexpr int NREP  = 2 * NBH;              // N-frags per wave
    constexpr int MPP   = (NBH == 2) ? 2 : 4;   // M-frags per phase (16 MFMA/phase both)
    constexpr int HALF  = 16384;                // 128x64 bf16 bytes
    constexpr int NHALF = 2 + NBH;
    constexpr int BUFB  = NHALF * HALF;
    __shared__ __align__(16) char lds[2 * BUFB];

    const int tid  = threadIdx.x;
    const int wid  = tid >> 6, lane = tid & 63;
    const int wr   = wid >> 2, wcn = wid & 3;

    // T1: bijective XCD-chunked swizzle (grid % 8 == 0)
    const int cpx     = (int)gridDim.x >> 3;
    const int logical = ((int)blockIdx.x & 7) * cpx + ((int)blockIdx.x >> 3);
    const int by = logical / nbx, bx = logical - by * nbx;
    const int bm = by * 256, bn = bx * (NBH * 128);

    // ---- staging source offsets (source carries the inverse swizzle; LDS dest linear)
    const int      r0   = tid >> 3;                                   // LDS row (j=0)
    const uint32_t cswz = (uint32_t)(((tid & 7) ^ (r0 & 7)) << 3);    // swizzled granule * 8 elems
    uint32_t offA[2], offB[NBH];
#pragma unroll
    for (int h = 0; h < 2; ++h)    offA[h] = (uint32_t)(bm + h * 128 + r0) * (uint32_t)K + cswz;
#pragma unroll
    for (int h = 0; h < NBH; ++h)  offB[h] = (uint32_t)(bn + h * 128 + r0) * (uint32_t)K + cswz;

#define STGH(G, P, HI, EOFF) do {                                                             \
    _Pragma("unroll") for (int j_ = 0; j_ < 2; ++j_)                                          \
        __builtin_amdgcn_global_load_lds(                                                     \
            (const __attribute__((address_space(1))) uint32_t*)((G) + (size_t)(EOFF) + (size_t)(j_ * 64) * (size_t)K), \
            (__attribute__((address_space(3))) uint32_t*)(lds + (P) * BUFB + (HI) * HALF + j_ * 8192 + wid * 1024), \
            16, 0, 0);                                                                        \
} while (0)

    // ---- ds_read bases (swizzled); frag m at +m*2048, kk flips granule bit2 = byte bit6
    const int      lrow = lane & 15, kg8 = lane >> 4;
    const uint32_t swz  = (uint32_t)((kg8 ^ (lrow & 7)) << 4);
    const uint32_t sAb  = (uint32_t)(wr * HALF) + (uint32_t)(lrow * 128) + swz;
    const int      colt0 = wcn * (NREP * 16);
    const uint32_t sBb  = (uint32_t)((2 + (colt0 >> 7)) * HALF) + (uint32_t)(((colt0 & 127) + lrow) * 128) + swz;

#define RD(o) (*reinterpret_cast<const bf16x8*>(lds + (o)))

    bf16x8 bf[NREP][2];   // B-frags, live across the K-tile's phases
    bf16x8 af[MPP][2];    // A-frags, per phase
    f32x4 acc[8][NREP];
#pragma unroll
    for (int m = 0; m < 8; ++m)
#pragma unroll
        for (int n = 0; n < NREP; ++n) acc[m][n] = (f32x4){0.f, 0.f, 0.f, 0.f};

#define RDBF(P) do {                                                                          \
    _Pragma("unroll") for (int n_ = 0; n_ < NREP; ++n_)                                       \
      _Pragma("unroll") for (int k_ = 0; k_ < 2; ++k_)                                        \
        bf[n_][k_] = RD((uint32_t)((P) * BUFB) + ((sBb + (uint32_t)(n_ * 2048)) ^ (uint32_t)(k_ << 6))); \
} while (0)

#define RDAF(P, M0) do {                                                                      \
    _Pragma("unroll") for (int m_ = 0; m_ < MPP; ++m_)                                        \
      _Pragma("unroll") for (int k_ = 0; k_ < 2; ++k_)                                        \
        af[m_][k_] = RD((uint32_t)((P) * BUFB) + ((sAb + (uint32_t)((((M0) + m_) * 2048))) ^ (uint32_t)(k_ << 6))); \
} while (0)

#define MFMAQ(M0) do {                                                                        \
    _Pragma("unroll") for (int m_ = 0; m_ < MPP; ++m_)                                        \
      _Pragma("unroll") for (int n_ = 0; n_ < NREP; ++n_)                                     \
        _Pragma("unroll") for (int k_ = 0; k_ < 2; ++k_)                                      \
          acc[(M0) + m_][n_] = __builtin_amdgcn_mfma_f32_16x16x32_bf16(af[m_][k_], bf[n_][k_], acc[(M0) + m_][n_], 0, 0, 0); \
} while (0)

#define VMC(NSTR) do { asm volatile("s_waitcnt vmcnt(" NSTR ")" ::: "memory");                \
                       __builtin_amdgcn_sched_barrier(0); } while (0)

// one phase: reads -> stage -> barrier -> lgkm(0) -> 16 MFMA -> [wait] -> barrier
#define PH(P, M0, FIRSTP, STAGES, WAITS, TRAILB) do {                                         \
    if (FIRSTP) RDBF(P);                                                                      \
    RDAF(P, M0);                                                                              \
    STAGES                                                                                    \
    __builtin_amdgcn_s_barrier();                                                             \
    asm volatile("s_waitcnt lgkmcnt(0)" ::: "memory");                                        \
    __builtin_amdgcn_sched_barrier(0);                                                        \
    __builtin_amdgcn_s_setprio(1);                                                            \
    MFMAQ(M0);                                                                                \
    __builtin_amdgcn_s_setprio(0);                                                            \
    __builtin_amdgcn_sched_barrier(0);                                                        \
    WAITS                                                                                     \
    if (TRAILB) { __builtin_amdgcn_s_barrier(); __builtin_amdgcn_sched_barrier(0); }          \
} while (0)

    // -------- prologue: tile0 complete + tile1 B-halves in flight
    if constexpr (NBH == 2) {
        STGH(A, 0, 0, offA[0]); STGH(A, 0, 1, offA[1]);
        STGH(Bt, 0, 2, offB[0]); STGH(Bt, 0, 3, offB[1]);
        STGH(Bt, 1, 2, offB[0] + 64); STGH(Bt, 1, 3, offB[1] + 64);
        VMC("4");                           // tile0's 8 loads landed; tile1-B (4) in flight
    } else {
        STGH(A, 0, 0, offA[0]); STGH(A, 0, 1, offA[1]); STGH(Bt, 0, 2, offB[0]);
        STGH(Bt, 1, 2, offB[0] + 64);
        VMC("2");                           // tile0's 6 landed; tile1-B (2) in flight
    }
    __builtin_amdgcn_s_barrier();
    __builtin_amdgcn_sched_barrier(0);

    // -------- main loop: iteration i computes tiles 2i (buf0), 2i+1 (buf1)
    const int NIT = NT >> 1;
    for (int i = 0; i < NIT - 1; ++i) {
        const uint32_t k1 = (uint32_t)(2 * i + 1) * 64u;
        const uint32_t k2 = (uint32_t)(2 * i + 2) * 64u;
        const uint32_t k3 = (uint32_t)(2 * i + 3) * 64u;
        if constexpr (NBH == 2) {
            PH(0, 0, true,  { STGH(A, 1, 0, offA[0] + k1); }, , true);
            PH(0, 2, false, { STGH(A, 1, 1, offA[1] + k1); }, , true);
            PH(0, 4, false, { STGH(Bt, 0, 2, offB[0] + k2); }, , true);
            PH(0, 6, false, { STGH(Bt, 0, 3, offB[1] + k2); }, VMC("4");, true);
            PH(1, 0, true,  { STGH(A, 0, 0, offA[0] + k2); }, , true);
            PH(1, 2, false, { STGH(A, 0, 1, offA[1] + k2); }, , true);
            PH(1, 4, false, { STGH(Bt, 1, 2, offB[0] + k3); }, , true);
            PH(1, 6, false, { STGH(Bt, 1, 3, offB[1] + k3); }, VMC("4");, true);
        } else {
            PH(0, 0, true,  { STGH(A, 1, 0, offA[0] + k1); STGH(A, 1, 1, offA[1] + k1); }, , true);
            PH(0, 4, false, { STGH(Bt, 0, 2, offB[0] + k2); }, VMC("2");, true);
            PH(1, 0, true,  { STGH(A, 0, 0, offA[0] + k2); STGH(A, 0, 1, offA[1] + k2); }, , true);
            PH(1, 4, false, { STGH(Bt, 1, 2, offB[0] + k3); }, VMC("2");, true);
        }
    }
    // -------- final iteration: tiles NT-2, NT-1; only tile NT-1's A-halves left to stage
    {
        const uint32_t kl = (uint32_t)(NT - 1) * 64u;
        if constexpr (NBH == 2) {
            PH(0, 0, true,  { STGH(A, 1, 0, offA[0] + kl); }, , true);
            PH(0, 2, false, { STGH(A, 1, 1, offA[1] + kl); }, , true);
            PH(0, 4, false, , , true);
            PH(0, 6, false, , VMC("0");, true);
            PH(1, 0, true,  , , true);
            PH(1, 2, false, , , true);
            PH(1, 4, false, , , true);
            PH(1, 6, false, , , false);
        } else {
            PH(0, 0, true,  { STGH(A, 1, 0, offA[0] + kl); STGH(A, 1, 1, offA[1] + kl); }, , true);
            PH(0, 4, false, , VMC("0");, true);
            PH(1, 0, true,  , , true);
            PH(1, 4, false, , , false);
        }
    }

    // -------- epilogue: C/D layout col = lane&15, row = (lane>>4)*4 + j
    const int crow0 = bm + wr * 128 + (kg8 << 2);
    const int ccol0 = bn + colt0 + lrow;

    if (EPI == 1) {
        bf16* __restrict__ Ho = (bf16*)Cout;
#pragma unroll
        for (int n = 0; n < NREP; ++n) {
            const int col = ccol0 + n * 16;
            const bool left = col < H_DIM;
            const float bias = left ? bias_l[col] : bias_r[col - H_DIM];
#pragma unroll
            for (int m = 0; m < 8; ++m) {
#pragma unroll
                for (int j = 0; j < 4; ++j) {
                    const int row = crow0 + m * 16 + j;
                    const float pw = p[row];
                    const float scale = left ? pw : 1.f - pw;
                    const float v = fmaxf(acc[m][n][j] + bias, 0.f) * scale;
                    Ho[(size_t)row * N + col] = __float2bfloat16(v);
                }
            }
        }
    } else {
        float* __restrict__ Co = (float*)Cout;
#pragma unroll
        for (int n = 0; n < NREP; ++n) {
            const int col = ccol0 + n * 16;
            const float bl = bias_l[col];
            const float brr = bias_r[col];
#pragma unroll
            for (int m = 0; m < 8; ++m) {
#pragma unroll
                for (int j = 0; j < 4; ++j) {
                    const int row = crow0 + m * 16 + j;
                    const float pw = p[row];
                    Co[(size_t)row * N + col] = acc[m][n][j] + pw * bl + (1.f - pw) * brr;
                }
            }
        }
    }
#undef PH
#undef VMC
#undef MFMAQ
#undef RDAF
#undef RDBF
#undef RD
#undef STGH
}

// ---------------------------------------------------------------- launch
extern "C" void kernel_launch(void* const* d_in, const int* in_sizes, int n_in,
                              void* d_out, int out_size, void* d_ws, size_t ws_size,
                              hipStream_t stream) {
    const float* x   = (const float*)d_in[0];
    const float* Wr  = (const float*)d_in[1];
    const float* br  = (const float*)d_in[2];
    const float* W1l = (const float*)d_in[3];
    const float* b1l = (const float*)d_in[4];
    const float* W2l = (const float*)d_in[5];
    const float* b2l = (const float*)d_in[6];
    const float* W1r = (const float*)d_in[7];
    const float* b1r = (const float*)d_in[8];
    const float* W2r = (const float*)d_in[9];
    const float* b2r = (const float*)d_in[10];
    float* out = (float*)d_out;

    char* ws = (char*)d_ws;
    // workspace layout (~160 MB):
    //   [0,16MB)     x_bf16 [B][D] bf16   (dead after gemm1; reused for W2t)
    //   [16,32MB)    W1t    [2H][D] bf16
    //   [32,160MB)   h      [B][2H] bf16
    //   [160MB,+32K) p      [B] f32
    bf16*  x_bf = (bf16*)(ws);
    bf16*  W1t  = (bf16*)(ws + (size_t)(16u << 20));
    bf16*  hbuf = (bf16*)(ws + (size_t)(32u << 20));
    float* pbuf = (float*)(ws + (size_t)(160u << 20));
    bf16*  W2t  = x_bf;   // aliased: written only after gemm1 consumed x_bf

    cast_f32_to_bf16<<<(B_DIM * D_DIM / 8 + 255) / 256, 256, 0, stream>>>(x, x_bf, B_DIM * D_DIM / 8);
    router_kernel<<<B_DIM / 4, 256, 0, stream>>>(x, Wr, br, pbuf);

    // W1t[n][k]: n<H -> W1l[k][n], else W1r[k][n-H]
    transpose_cast_kernel<<<dim3(H_DIM / 32, D_DIM / 32), 256, 0, stream>>>(W1l, D_DIM, H_DIM, W1t, D_DIM);
    transpose_cast_kernel<<<dim3(H_DIM / 32, D_DIM / 32), 256, 0, stream>>>(W1r, D_DIM, H_DIM,
                                                                            W1t + (size_t)H_DIM * D_DIM, D_DIM);
    // h = relu(x @ W1cat + b1cat) * {p | 1-p}   -> bf16 [B][2H]
    // grid 32x32=1024 blocks, BM=256, BN=256, NT=16, nbx=32
    gemm8<2, 1><<<1024, 512, 0, stream>>>(x_bf, W1t, hbuf, H2_DIM, D_DIM, D_DIM / 64, 32,
                                          pbuf, b1l, b1r);

    // W2t[n][k]: k<H -> W2l[k][n], else W2r[k-H][n]
    transpose_cast_kernel<<<dim3(D_DIM / 32, H_DIM / 32), 256, 0, stream>>>(W2l, H_DIM, D_DIM, W2t, H2_DIM);
    transpose_cast_kernel<<<dim3(D_DIM / 32, H_DIM / 32), 256, 0, stream>>>(W2r, H_DIM, D_DIM, W2t + H_DIM, H2_DIM);

    // out = h @ W2cat + p*b2l + (1-p)*b2r    -> f32 [B][D]
    // grid 32x8=256 blocks, BM=256, BN=128, NT=128, nbx=8
    gemm8<1, 0><<<256, 512, 0, stream>>>(hbuf, W2t, out, D_DIM, H2_DIM, H2_DIM / 64, 8,
                                         pbuf, b2l, b2r);
}

// Round 8
// 431.832 us; speedup vs baseline: 1.0696x; 1.0696x over previous
//
#include <hip/hip_runtime.h>
#include <hip/hip_bf16.h>
#include <cstdint>
#include <cstddef>

#define B_DIM  8192
#define D_DIM  1024
#define H_DIM  4096
#define H2_DIM 8192

using bf16 = __hip_bfloat16;
typedef __attribute__((ext_vector_type(8))) short bf16x8;   // 8 bf16 in 4 VGPRs
typedef __attribute__((ext_vector_type(4))) float f32x4;    // MFMA accumulator

// ---------------------------------------------------------------- cast x -> bf16
__global__ __launch_bounds__(256) void cast_f32_to_bf16(const float* __restrict__ in,
                                                        bf16* __restrict__ out, int n_vec8) {
    int i = blockIdx.x * 256 + threadIdx.x;
    if (i >= n_vec8) return;
    const float4* src = reinterpret_cast<const float4*>(in) + (size_t)i * 2;
    float4 a = src[0], b = src[1];
    union { bf16 h[8]; int4 u; } r;
    r.h[0] = __float2bfloat16(a.x); r.h[1] = __float2bfloat16(a.y);
    r.h[2] = __float2bfloat16(a.z); r.h[3] = __float2bfloat16(a.w);
    r.h[4] = __float2bfloat16(b.x); r.h[5] = __float2bfloat16(b.y);
    r.h[6] = __float2bfloat16(b.z); r.h[7] = __float2bfloat16(b.w);
    reinterpret_cast<int4*>(out)[i] = r.u;
}

// ---------------------------------------------------------------- router p = sigmoid(x.Wr + br)
__global__ __launch_bounds__(256) void router_kernel(const float* __restrict__ x,
                                                     const float* __restrict__ Wr,
                                                     const float* __restrict__ br,
                                                     float* __restrict__ p) {
    int wave = threadIdx.x >> 6, lane = threadIdx.x & 63;
    int row = blockIdx.x * 4 + wave;
    const float* xr = x + (size_t)row * D_DIM;
    float sum = 0.f;
#pragma unroll
    for (int it = 0; it < 4; ++it) {
        int k = it * 256 + lane * 4;
        float4 xv = *reinterpret_cast<const float4*>(xr + k);
        float4 wv = *reinterpret_cast<const float4*>(Wr + k);
        sum += xv.x * wv.x + xv.y * wv.y + xv.z * wv.z + xv.w * wv.w;
    }
#pragma unroll
    for (int off = 32; off >= 1; off >>= 1) sum += __shfl_down(sum, off, 64);
    if (lane == 0) p[row] = 1.f / (1.f + expf(-(sum + br[0])));
}

// ---------------------------------------------------------------- 64x64 transpose+cast, l/r pair fused
// dst[(c0+gr)*dstLD + r0+rc] = bf16(src[r0+rc][c0+gr]); packed 2-col (bf16x2) writes, 128B/row segment
__global__ __launch_bounds__(256) void transpose_cast2(const float* __restrict__ srcA,
                                                       const float* __restrict__ srcB,
                                                       int C,
                                                       bf16* __restrict__ dstA,
                                                       bf16* __restrict__ dstB, int dstLD) {
    __shared__ float tile[64][65];
    const float* src = blockIdx.z ? srcB : srcA;
    bf16*       dst = blockIdx.z ? dstB : dstA;
    const int c0 = blockIdx.x * 64, r0 = blockIdx.y * 64;
    const int tx = threadIdx.x & 63, ty = threadIdx.x >> 6;   // ty: 0..3
#pragma unroll
    for (int k = 0; k < 16; ++k)
        tile[k * 4 + ty][tx] = src[(size_t)(r0 + k * 4 + ty) * C + c0 + tx];
    __syncthreads();
#pragma unroll
    for (int k = 0; k < 8; ++k) {
        const int gr = k * 8 + (threadIdx.x >> 5);   // transposed row (source col)
        const int rc = (threadIdx.x & 31) * 2;       // source row pair
        union { bf16 h[2]; uint32_t u; } w;
        w.h[0] = __float2bfloat16(tile[rc][gr]);
        w.h[1] = __float2bfloat16(tile[rc + 1][gr]);
        *reinterpret_cast<uint32_t*>(&dst[(size_t)(c0 + gr) * dstLD + r0 + rc]) = w.u;
    }
}

// ================================================================ quadrant-phase counted-vmcnt GEMM
// C = A[M,K] * Bt[N,K]^T. BM=256, BN=NBH*128, BK=64, 512 threads (8 waves, 2M x 4N).
// LDS halves per K-tile: A0,A1 (idx 0,1) + B0[,B1] (idx 2[,3]); 2 buffers.
// Phase = one C-quadrant (Mhalf x Nhalf) x K=64 = 16 MFMA, 4-12 ds_read_b128, exactly one
// staged half (2 global_load_lds). Balanced reads keep LDS exposure ~ MFMA issue (m201 62%).
// NBH=2 per-tile slots: q0(A0,B0)+stg A0(u+1) | q1(A1,B0)+stg B1(u+1) | q2(A1,B1)+stg B0(u+2)
//   | q3(A0,B1)+stg A1(u+2)+VMC(4). Stage-into-live-buffer is safe: each phase's ds_reads are
//   lgkm(0)-drained before its trailing barrier, and stages issue after that barrier.
// NBH=1: p0(A0,B)+stg B(u+1),A1(u+1) | p1(A1,B)+stg A0(u+2)+VMC(2).
// Waits are counted (never 0 mid-loop): 2-tile prefetch depth covers ~900cy HBM latency.
template<int NBH, int EPI>
__global__ __launch_bounds__(512, 2) void gemm8(const bf16* __restrict__ A,
                                                const bf16* __restrict__ Bt,
                                                void* __restrict__ Cout,
                                                int N, int K, int NT, int nbx,
                                                const float* __restrict__ p,
                                                const float* __restrict__ bias_l,
                                                const float* __restrict__ bias_r) {
    constexpr int NREP  = 2 * NBH;
    constexpr int HALF  = 16384;                 // 128x64 bf16 bytes
    constexpr int NHALF = 2 + NBH;
    constexpr int BUFB  = NHALF * HALF;
    constexpr int EP_PITCH = 264;                // epilogue bounce: 256 + 8 pad bf16 per row
    constexpr size_t LDSB = (EPI == 1 && (size_t)256 * EP_PITCH * 2 > (size_t)2 * BUFB)
                              ? (size_t)256 * EP_PITCH * 2 : (size_t)2 * BUFB;
    __shared__ __align__(16) char lds[LDSB];

    const int tid  = threadIdx.x;
    const int wid  = tid >> 6, lane = tid & 63;
    const int wr   = wid >> 2, wcn = wid & 3;

    // T1: bijective XCD-chunked swizzle (grid % 8 == 0)
    const int cpx     = (int)gridDim.x >> 3;
    const int logical = ((int)blockIdx.x & 7) * cpx + ((int)blockIdx.x >> 3);
    const int by = logical / nbx, bx = logical - by * nbx;
    const int bm = by * 256, bn = bx * (NBH * 128);

    // ---- staging source offsets (source carries the inverse swizzle; LDS dest linear)
    const int      r0   = tid >> 3;
    const uint32_t cswz = (uint32_t)(((tid & 7) ^ (r0 & 7)) << 3);
    uint32_t offA[2], offB[NBH];
#pragma unroll
    for (int h = 0; h < 2; ++h)    offA[h] = (uint32_t)(bm + h * 128 + r0) * (uint32_t)K + cswz;
#pragma unroll
    for (int h = 0; h < NBH; ++h)  offB[h] = (uint32_t)(bn + h * 128 + r0) * (uint32_t)K + cswz;

#define STGH(G, P, HI, EOFF) do {                                                             \
    _Pragma("unroll") for (int j_ = 0; j_ < 2; ++j_)                                          \
        __builtin_amdgcn_global_load_lds(                                                     \
            (const __attribute__((address_space(1))) uint32_t*)((G) + (size_t)(EOFF) + (size_t)(j_ * 64) * (size_t)K), \
            (__attribute__((address_space(3))) uint32_t*)(lds + (P) * BUFB + (HI) * HALF + j_ * 8192 + wid * 1024), \
            16, 0, 0);                                                                        \
} while (0)

    // ---- ds_read bases (T2 swizzled; frag f at +f*2048, kk flips byte bit6)
    const int      lrow = lane & 15, kg8 = lane >> 4;
    const uint32_t swz  = (uint32_t)((kg8 ^ (lrow & 7)) << 4);
    const uint32_t sAb  = (uint32_t)(wr * HALF) + (uint32_t)(lrow * 128) + swz;
    const int      colt0 = wcn * (NREP * 16);
    const uint32_t sBb  = (uint32_t)((2 + (colt0 >> 7)) * HALF) + (uint32_t)(((colt0 & 127) + lrow) * 128) + swz;

#define RD(o) (*reinterpret_cast<const bf16x8*>(lds + (o)))

    bf16x8 bf[2][2];      // current B-half frags
    bf16x8 af[4][2];      // current A-half frags
    f32x4 acc[8][NREP];
#pragma unroll
    for (int m = 0; m < 8; ++m)
#pragma unroll
        for (int n = 0; n < NREP; ++n) acc[m][n] = (f32x4){0.f, 0.f, 0.f, 0.f};

#define RDA(P, MH) do {                                                                       \
    _Pragma("unroll") for (int m_ = 0; m_ < 4; ++m_)                                          \
      _Pragma("unroll") for (int k_ = 0; k_ < 2; ++k_)                                        \
        af[m_][k_] = RD((uint32_t)((P) * BUFB) + ((sAb + (uint32_t)((((MH) * 4 + m_) * 2048))) ^ (uint32_t)(k_ << 6))); \
} while (0)

#define RDB(P, NH) do {                                                                       \
    _Pragma("unroll") for (int n_ = 0; n_ < 2; ++n_)                                          \
      _Pragma("unroll") for (int k_ = 0; k_ < 2; ++k_)                                        \
        bf[n_][k_] = RD((uint32_t)((P) * BUFB) + ((sBb + (uint32_t)((((NH) * 2 + n_) * 2048))) ^ (uint32_t)(k_ << 6))); \
} while (0)

#define MFMAQ(MH, NH) do {                                                                    \
    _Pragma("unroll") for (int m_ = 0; m_ < 4; ++m_)                                          \
      _Pragma("unroll") for (int n_ = 0; n_ < 2; ++n_)                                        \
        _Pragma("unroll") for (int k_ = 0; k_ < 2; ++k_)                                      \
          acc[(MH) * 4 + m_][(NH) * 2 + n_] =                                                 \
            __builtin_amdgcn_mfma_f32_16x16x32_bf16(af[m_][k_], bf[n_][k_],                   \
                                                    acc[(MH) * 4 + m_][(NH) * 2 + n_], 0, 0, 0); \
} while (0)

#define VMC(NSTR) do { asm volatile("s_waitcnt vmcnt(" NSTR ")" ::: "memory");                \
                       __builtin_amdgcn_sched_barrier(0); } while (0)

// phase: reads -> stage -> barrier -> lgkm(0) -> 16 MFMA -> [wait] -> [barrier]
#define PH(RR, MH, NH, STG, WT, TB) do {                                                      \
    RR                                                                                        \
    STG                                                                                       \
    __builtin_amdgcn_s_barrier();                                                             \
    asm volatile("s_waitcnt lgkmcnt(0)" ::: "memory");                                        \
    __builtin_amdgcn_sched_barrier(0);                                                        \
    __builtin_amdgcn_s_setprio(1);                                                            \
    MFMAQ(MH, NH);                                                                            \
    __builtin_amdgcn_s_setprio(0);                                                            \
    __builtin_amdgcn_sched_barrier(0);                                                        \
    WT                                                                                        \
    if (TB) { __builtin_amdgcn_s_barrier(); __builtin_amdgcn_sched_barrier(0); }              \
} while (0)

    if constexpr (NBH == 2) {
        // prologue: tile0 complete (8) + B0(1),A1(1) (4) in flight
        STGH(A, 0, 0, offA[0]); STGH(A, 0, 1, offA[1]);
        STGH(Bt, 0, 2, offB[0]); STGH(Bt, 0, 3, offB[1]);
        STGH(Bt, 1, 2, offB[0] + 64); STGH(A, 1, 1, offA[1] + 64);
        VMC("4");
        __builtin_amdgcn_s_barrier();
        __builtin_amdgcn_sched_barrier(0);

        // steady tiles 0..NT-3 (pair-unrolled; NT even)
        for (int i = 0; i < (NT - 2) / 2; ++i) {
            const uint32_t k1 = (uint32_t)(2 * i + 1) * 64u;
            const uint32_t k2 = (uint32_t)(2 * i + 2) * 64u;
            const uint32_t k3 = (uint32_t)(2 * i + 3) * 64u;
            // tile 2i (buf0), stages into buf1 (u+1) then buf0 (u+2)
            PH({RDA(0,0); RDB(0,0);}, 0, 0, {STGH(A, 1, 0, offA[0] + k1);}, , true);
            PH({RDA(0,1);},           1, 0, {STGH(Bt, 1, 3, offB[1] + k1);}, , true);
            PH({RDB(0,1);},           1, 1, {STGH(Bt, 0, 2, offB[0] + k2);}, , true);
            PH({RDA(0,0);},           0, 1, {STGH(A, 0, 1, offA[1] + k2);}, VMC("4");, true);
            // tile 2i+1 (buf1)
            PH({RDA(1,0); RDB(1,0);}, 0, 0, {STGH(A, 0, 0, offA[0] + k2);}, , true);
            PH({RDA(1,1);},           1, 0, {STGH(Bt, 0, 3, offB[1] + k2);}, , true);
            PH({RDB(1,1);},           1, 1, {STGH(Bt, 1, 2, offB[0] + k3);}, , true);
            PH({RDA(1,0);},           0, 1, {STGH(A, 1, 1, offA[1] + k3);}, VMC("4");, true);
        }
        // tile NT-2 (buf0): stage only tile NT-1's A0,B1; drain all
        {
            const uint32_t kl = (uint32_t)(NT - 1) * 64u;
            PH({RDA(0,0); RDB(0,0);}, 0, 0, {STGH(A, 1, 0, offA[0] + kl);}, , true);
            PH({RDA(0,1);},           1, 0, {STGH(Bt, 1, 3, offB[1] + kl);}, , true);
            PH({RDB(0,1);},           1, 1, , , true);
            PH({RDA(0,0);},           0, 1, , VMC("0");, true);
        }
        // tile NT-1 (buf1): no stages
        PH({RDA(1,0); RDB(1,0);}, 0, 0, , , true);
        PH({RDA(1,1);},           1, 0, , , true);
        PH({RDB(1,1);},           1, 1, , , true);
        PH({RDA(1,0);},           0, 1, , , false);
    } else {
        // prologue: tile0 complete (6) + A0(1) (2) in flight
        STGH(A, 0, 0, offA[0]); STGH(A, 0, 1, offA[1]); STGH(Bt, 0, 2, offB[0]);
        STGH(A, 1, 0, offA[0] + 64);
        VMC("2");
        __builtin_amdgcn_s_barrier();
        __builtin_amdgcn_sched_barrier(0);

        for (int i = 0; i < (NT - 2) / 2; ++i) {
            const uint32_t k1 = (uint32_t)(2 * i + 1) * 64u;
            const uint32_t k2 = (uint32_t)(2 * i + 2) * 64u;
            const uint32_t k3 = (uint32_t)(2 * i + 3) * 64u;
            // tile 2i (buf0)
            PH({RDA(0,0); RDB(0,0);}, 0, 0, {STGH(Bt, 1, 2, offB[0] + k1); STGH(A, 1, 1, offA[1] + k1);}, , true);
            PH({RDA(0,1);},           1, 0, {STGH(A, 0, 0, offA[0] + k2);}, VMC("2");, true);
            // tile 2i+1 (buf1)
            PH({RDA(1,0); RDB(1,0);}, 0, 0, {STGH(Bt, 0, 2, offB[0] + k2); STGH(A, 0, 1, offA[1] + k2);}, , true);
            PH({RDA(1,1);},           1, 0, {STGH(A, 1, 0, offA[0] + k3);}, VMC("2");, true);
        }
        {
            const uint32_t kl = (uint32_t)(NT - 1) * 64u;
            PH({RDA(0,0); RDB(0,0);}, 0, 0, {STGH(Bt, 1, 2, offB[0] + kl); STGH(A, 1, 1, offA[1] + kl);}, , true);
            PH({RDA(0,1);},           1, 0, , VMC("0");, true);
        }
        PH({RDA(1,0); RDB(1,0);}, 0, 0, , , true);
        PH({RDA(1,1);},           1, 0, , , false);
    }

    // -------- epilogue: C/D layout col = lane&15, row = (lane>>4)*4 + j
    if (EPI == 1) {
        // LDS-bounce for full-line coalesced bf16 writes (fixes 2x HBM write amplification)
        __builtin_amdgcn_s_barrier();     // all lds reads done before reuse
        bf16* __restrict__ Ho = (bf16*)Cout;
        bf16* elds = (bf16*)lds;
        const int er0 = wr * 128 + (kg8 << 2);
        float biasv[4];
        bool  leftv[4];
#pragma unroll
        for (int n = 0; n < 4; ++n) {
            const int col = bn + colt0 + n * 16 + lrow;
            leftv[n] = col < H_DIM;
            biasv[n] = leftv[n] ? bias_l[col] : bias_r[col - H_DIM];
        }
#pragma unroll
        for (int m = 0; m < 8; ++m) {
#pragma unroll
            for (int j = 0; j < 4; ++j) {
                const int rl = er0 + m * 16 + j;
                const float pw = p[bm + rl];
#pragma unroll
                for (int n = 0; n < 4; ++n) {
                    const float scale = leftv[n] ? pw : 1.f - pw;
                    const float v = fmaxf(acc[m][n][j] + biasv[n], 0.f) * scale;
                    elds[rl * EP_PITCH + colt0 + n * 16 + lrow] = __float2bfloat16(v);
                }
            }
        }
        __builtin_amdgcn_s_barrier();
#pragma unroll
        for (int r = 0; r < 16; ++r) {
            const int rl = r * 16 + (tid >> 5);
            const int cb = (tid & 31) * 8;
            int4 v = *reinterpret_cast<const int4*>(&elds[rl * EP_PITCH + cb]);
            *reinterpret_cast<int4*>(&Ho[(size_t)(bm + rl) * N + bn + cb]) = v;
        }
    } else {
        float* __restrict__ Co = (float*)Cout;
        const int crow0 = bm + wr * 128 + (kg8 << 2);
        const int ccol0 = bn + colt0 + lrow;
#pragma unroll
        for (int n = 0; n < NREP; ++n) {
            const int col = ccol0 + n * 16;
            const float bl = bias_l[col];
            const float brr = bias_r[col];
#pragma unroll
            for (int m = 0; m < 8; ++m) {
#pragma unroll
                for (int j = 0; j < 4; ++j) {
                    const int row = crow0 + m * 16 + j;
                    const float pw = p[row];
                    Co[(size_t)row * N + col] = acc[m][n][j] + pw * bl + (1.f - pw) * brr;
                }
            }
        }
    }
#undef PH
#undef VMC
#undef MFMAQ
#undef RDB
#undef RDA
#undef RD
#undef STGH
}

// ---------------------------------------------------------------- launch
extern "C" void kernel_launch(void* const* d_in, const int* in_sizes, int n_in,
                              void* d_out, int out_size, void* d_ws, size_t ws_size,
                              hipStream_t stream) {
    const float* x   = (const float*)d_in[0];
    const float* Wr  = (const float*)d_in[1];
    const float* br  = (const float*)d_in[2];
    const float* W1l = (const float*)d_in[3];
    const float* b1l = (const float*)d_in[4];
    const float* W2l = (const float*)d_in[5];
    const float* b2l = (const float*)d_in[6];
    const float* W1r = (const float*)d_in[7];
    const float* b1r = (const float*)d_in[8];
    const float* W2r = (const float*)d_in[9];
    const float* b2r = (const float*)d_in[10];
    float* out = (float*)d_out;

    char* ws = (char*)d_ws;
    // workspace layout (~160 MB):
    //   [0,16MB)     x_bf16 [B][D] bf16   (dead after gemm1; reused for W2t)
    //   [16,32MB)    W1t    [2H][D] bf16
    //   [32,160MB)   h      [B][2H] bf16
    //   [160MB,+32K) p      [B] f32
    bf16*  x_bf = (bf16*)(ws);
    bf16*  W1t  = (bf16*)(ws + (size_t)(16u << 20));
    bf16*  hbuf = (bf16*)(ws + (size_t)(32u << 20));
    float* pbuf = (float*)(ws + (size_t)(160u << 20));
    bf16*  W2t  = x_bf;   // aliased: written only after gemm1 consumed x_bf

    cast_f32_to_bf16<<<(B_DIM * D_DIM / 8 + 255) / 256, 256, 0, stream>>>(x, x_bf, B_DIM * D_DIM / 8);
    router_kernel<<<B_DIM / 4, 256, 0, stream>>>(x, Wr, br, pbuf);

    // W1t[n][k]: n<H -> W1l[k][n], else W1r[k][n-H]   (src [1024][4096])
    transpose_cast2<<<dim3(H_DIM / 64, D_DIM / 64, 2), 256, 0, stream>>>(
        W1l, W1r, H_DIM, W1t, W1t + (size_t)H_DIM * D_DIM, D_DIM);

    // h = relu(x @ W1cat + b1cat) * {p | 1-p}   -> bf16 [B][2H]
    gemm8<2, 1><<<1024, 512, 0, stream>>>(x_bf, W1t, hbuf, H2_DIM, D_DIM, D_DIM / 64, 32,
                                          pbuf, b1l, b1r);

    // W2t[n][k]: k<H -> W2l[k][n], else W2r[k-H][n]   (src [4096][1024])
    transpose_cast2<<<dim3(D_DIM / 64, H_DIM / 64, 2), 256, 0, stream>>>(
        W2l, W2r, D_DIM, W2t, W2t + H_DIM, H2_DIM);

    // out = h @ W2cat + p*b2l + (1-p)*b2r    -> f32 [B][D]
    gemm8<1, 0><<<256, 512, 0, stream>>>(hbuf, W2t, out, D_DIM, H2_DIM, H2_DIM / 64, 8,
                                         pbuf, b2l, b2r);
}